// Round 1
// baseline (777.052 us; speedup 1.0000x reference)
//
#include <hip/hip_runtime.h>
#include <hip/hip_bf16.h>
#include <stdint.h>

#define HID 1024
#define NB 32
#define NS 2048
#define NROWS (NB*NS)   // 65536

typedef short v8s __attribute__((ext_vector_type(8)));    // 8 x bf16 (as i16 bits) = 4 VGPR
typedef float v16f __attribute__((ext_vector_type(16)));  // 32x32 MFMA accumulator

__device__ __forceinline__ unsigned short f2bf(float f){
  union { float f; unsigned int u; } v; v.f = f;
  unsigned int u = v.u;
  u += 0x7FFFu + ((u >> 16) & 1u);   // RNE
  return (unsigned short)(u >> 16);
}

__device__ __forceinline__ uint4 pack8(const float4& a, const float4& b){
  uint4 r;
  r.x = (unsigned)f2bf(a.x) | ((unsigned)f2bf(a.y) << 16);
  r.y = (unsigned)f2bf(a.z) | ((unsigned)f2bf(a.w) << 16);
  r.z = (unsigned)f2bf(b.x) | ((unsigned)f2bf(b.y) << 16);
  r.w = (unsigned)f2bf(b.z) | ((unsigned)f2bf(b.w) << 16);
  return r;
}

// ---------------- K1: q_proj (fp32) + zero scores ----------------
__global__ __launch_bounds__(256) void k_qproj(const float* __restrict__ query,
                                               const float* __restrict__ Wq,
                                               float* __restrict__ qp,
                                               float* __restrict__ scores){
  int tid = threadIdx.x;
  int gw = ((blockIdx.x << 8) + tid) >> 6;   // wave id 0..32767
  int lane = tid & 63;
  int b = gw >> 10, o = gw & 1023;
  const float* qr = query + b*HID;
  const float* wr = Wq + (size_t)o*HID;
  float p = 0.f;
#pragma unroll
  for (int i = 0; i < 16; ++i){
    int h = lane + (i << 6);
    p += qr[h]*wr[h];
  }
#pragma unroll
  for (int m = 32; m >= 1; m >>= 1) p += __shfl_xor(p, m, 64);
  if (lane == 0) qp[gw] = p;
  // zero the 65536-entry score buffer: 8 floats per block
  if (tid < 8) scores[(blockIdx.x << 3) + tid] = 0.f;
}

// ---------------- K3: fused k_proj GEMM + tanh + V-dot -> partial scores ----------------
// grid 4096 = 512 m-tiles (128 rows) x 8 n-tiles (128 cols). bf16 MFMA 32x32x16.
__global__ __launch_bounds__(256) void k_scores(const float* __restrict__ keys,
                                                const float* __restrict__ Wk,
                                                const float* __restrict__ qp,
                                                const float* __restrict__ V,
                                                float* __restrict__ scores){
  __shared__ uint4 Ab[2][1024];   // [buf][kg*128+row] : 16B slot = 8 bf16 (k-contiguous)
  __shared__ uint4 Bb[2][1024];
  int bid = blockIdx.x;
  // XCD-chunked swizzle: hw xcd = bid%8; give each XCD contiguous v-range so the
  // 8 n-variants of an m-strip are temporally adjacent on one XCD (A L2 reuse).
  int v = ((bid & 7) << 9) | (bid >> 3);
  int mt = v >> 3, nt = v & 7;
  int m0 = mt << 7, n0 = nt << 7;
  int b = m0 >> 11;                 // 128 | 2048 -> whole tile in one batch
  int tid = threadIdx.x;
  int lane = tid & 63;
  int wid = tid >> 6;
  int wm = wid >> 1, wn = wid & 1;  // 2x2 wave grid, wave tile 64x64
  int l31 = lane & 31, hi = lane >> 5;

  int skg[4], srw[4];
#pragma unroll
  for (int i = 0; i < 4; ++i){
    int sidx = (i << 8) + tid;      // 1024 slots per tile
    skg[i] = sidx & 7;              // k-group (8 per BK=64)
    srw[i] = sidx >> 3;             // row/col 0..127
  }
  float4 ar[4][2], br[4][2];

  auto loadt = [&](int kt){
#pragma unroll
    for (int i = 0; i < 4; ++i){
      const float* as = keys + (size_t)(m0 + srw[i])*HID + (kt << 6) + (skg[i] << 3);
      ar[i][0] = *(const float4*)as;
      ar[i][1] = *(const float4*)(as + 4);
      const float* bs2 = Wk + (size_t)(n0 + srw[i])*HID + (kt << 6) + (skg[i] << 3);
      br[i][0] = *(const float4*)bs2;
      br[i][1] = *(const float4*)(bs2 + 4);
    }
  };
  auto writet = [&](int bsel){
#pragma unroll
    for (int i = 0; i < 4; ++i){
      int slot = (skg[i] << 7) + srw[i];
      Ab[bsel][slot] = pack8(ar[i][0], ar[i][1]);
      Bb[bsel][slot] = pack8(br[i][0], br[i][1]);
    }
  };

  v16f acc[2][2] = {};

  loadt(0);
  writet(0);
  __syncthreads();
  for (int kt = 0; kt < 16; ++kt){
    int bs = kt & 1;
    if (kt < 15) loadt(kt + 1);          // async issue; consumed after barrier
#pragma unroll
    for (int ks = 0; ks < 4; ++ks){
      int kg = (ks << 1) + hi;           // lane k-group: hi lanes take k+8..15
      int abase = (kg << 7) + (wm << 6) + l31;
      int bbase = (kg << 7) + (wn << 6) + l31;
      v8s a0 = __builtin_bit_cast(v8s, Ab[bs][abase]);
      v8s a1 = __builtin_bit_cast(v8s, Ab[bs][abase + 32]);
      v8s b0 = __builtin_bit_cast(v8s, Bb[bs][bbase]);
      v8s b1 = __builtin_bit_cast(v8s, Bb[bs][bbase + 32]);
      acc[0][0] = __builtin_amdgcn_mfma_f32_32x32x16_bf16(a0, b0, acc[0][0], 0, 0, 0);
      acc[0][1] = __builtin_amdgcn_mfma_f32_32x32x16_bf16(a0, b1, acc[0][1], 0, 0, 0);
      acc[1][0] = __builtin_amdgcn_mfma_f32_32x32x16_bf16(a1, b0, acc[1][0], 0, 0, 0);
      acc[1][1] = __builtin_amdgcn_mfma_f32_32x32x16_bf16(a1, b1, acc[1][1], 0, 0, 0);
    }
    if (kt < 15){
      __syncthreads();
      writet(bs ^ 1);
      __syncthreads();
    }
  }

  // epilogue: score_partial[row] += sum_o V[o]*tanh(qp[b][o] + kproj)
  float qpv[2], Vv[2];
#pragma unroll
  for (int ni = 0; ni < 2; ++ni){
    int o = n0 + (wn << 6) + (ni << 5) + l31;
    qpv[ni] = qp[(b << 10) + o];
    Vv[ni] = V[o];
  }
#pragma unroll
  for (int mi = 0; mi < 2; ++mi){
#pragma unroll
    for (int r = 0; r < 16; ++r){
      float sp = 0.f;
#pragma unroll
      for (int ni = 0; ni < 2; ++ni){
        float x = qpv[ni] + acc[mi][ni][r];
        float e = __expf(2.f*x);             // tanh = 1 - 2/(e^{2x}+1); inf-safe
        sp += Vv[ni]*(1.f - 2.f/(e + 1.f));
      }
#pragma unroll
      for (int m = 16; m >= 1; m >>= 1) sp += __shfl_xor(sp, m, 64);  // reduce 32 cols
      if (l31 == 0){
        // C/D map (32x32): col=lane&31, row=(r&3)+8*(r>>2)+4*hi
        int row = m0 + (wm << 6) + (mi << 5) + (r & 3) + ((r >> 2) << 3) + (hi << 2);
        atomicAdd(&scores[row], sp);
      }
    }
  }
}

// ---------------- K4: softmax over S per batch + zero context region ----------------
__global__ __launch_bounds__(256) void k_softmax(const float* __restrict__ scores,
                                                 float* __restrict__ out){
  int b = blockIdx.x; int tid = threadIdx.x;
  __shared__ float red[8];
  const float* srow = scores + b*NS;
  float vv[8];
  float mx = -1e30f;
#pragma unroll
  for (int i = 0; i < 8; ++i){ vv[i] = srow[tid + (i << 8)]; mx = fmaxf(mx, vv[i]); }
#pragma unroll
  for (int m = 32; m >= 1; m >>= 1) mx = fmaxf(mx, __shfl_xor(mx, m, 64));
  int wid = tid >> 6, lane = tid & 63;
  if (lane == 0) red[wid] = mx;
  __syncthreads();
  mx = fmaxf(fmaxf(red[0], red[1]), fmaxf(red[2], red[3]));
  float s = 0.f;
#pragma unroll
  for (int i = 0; i < 8; ++i){ vv[i] = __expf(vv[i] - mx); s += vv[i]; }
#pragma unroll
  for (int m = 32; m >= 1; m >>= 1) s += __shfl_xor(s, m, 64);
  if (lane == 0) red[4 + wid] = s;
  __syncthreads();
  s = red[4] + red[5] + red[6] + red[7];
  float inv = 1.f/s;
  float* wout = out + NB*HID + b*NS;
#pragma unroll
  for (int i = 0; i < 8; ++i) wout[tid + (i << 8)] = vv[i]*inv;
  // zero context region for this batch (K5 accumulates into it)
  float4* ctx = (float4*)(out + b*HID);
  ctx[tid] = make_float4(0.f, 0.f, 0.f, 0.f);
}

// ---------------- K5: context = weights @ keys (fp32) ----------------
__global__ __launch_bounds__(256) void k_context(const float* __restrict__ keys,
                                                 const float* __restrict__ w,
                                                 float* __restrict__ ctx){
  int blk = blockIdx.x;                 // 32 b x 4 hc x 8 sc
  int b = blk >> 5;
  int hc = (blk >> 3) & 3;
  int sc = blk & 7;
  int h = (hc << 8) + threadIdx.x;
  const float* wrow = w + b*NS + (sc << 8);
  const float* krow = keys + ((size_t)b*NS + (sc << 8))*HID + h;
  float a = 0.f;
#pragma unroll 4
  for (int s = 0; s < 256; ++s) a += wrow[s]*krow[(size_t)s*HID];
  atomicAdd(&ctx[b*HID + h], a);
}

extern "C" void kernel_launch(void* const* d_in, const int* in_sizes, int n_in,
                              void* d_out, int out_size, void* d_ws, size_t ws_size,
                              hipStream_t stream){
  const float* query = (const float*)d_in[0];
  const float* keys  = (const float*)d_in[1];
  const float* Wq    = (const float*)d_in[2];
  const float* Wk    = (const float*)d_in[3];
  const float* V     = (const float*)d_in[4];
  float* out = (float*)d_out;
  float* qp = (float*)d_ws;              // 32*1024 f32
  float* scores = qp + NB*HID;           // 32*2048 f32

  hipLaunchKernelGGL(k_qproj,   dim3(8192), dim3(256), 0, stream, query, Wq, qp, scores);
  hipLaunchKernelGGL(k_scores,  dim3(4096), dim3(256), 0, stream, keys, Wk, qp, V, scores);
  hipLaunchKernelGGL(k_softmax, dim3(32),   dim3(256), 0, stream, scores, out);
  hipLaunchKernelGGL(k_context, dim3(1024), dim3(256), 0, stream, keys, out + NB*HID, out);
}

// Round 3
// 774.388 us; speedup vs baseline: 1.0034x; 1.0034x over previous
//
#include <hip/hip_runtime.h>
#include <hip/hip_bf16.h>
#include <stdint.h>

#define HID 1024
#define NB 32
#define NS 2048
#define NROWS (NB*NS)   // 65536

typedef short v8s __attribute__((ext_vector_type(8)));    // 8 x bf16 (as i16 bits) = 4 VGPR
typedef float v16f __attribute__((ext_vector_type(16)));  // 32x32 MFMA accumulator

// packed f32x2 -> bf16x2 (RNE), 1 VALU op. Pair order is irrelevant for the
// GEMM: A and B get the identical k-permutation, dot-product invariant.
__device__ __forceinline__ unsigned cvt2(float a, float b){
  unsigned r;
  asm("v_cvt_pk_bf16_f32 %0, %1, %2" : "=v"(r) : "v"(a), "v"(b));
  return r;
}

__device__ __forceinline__ uint4 pack8(const float4& a, const float4& b){
  uint4 r;
  r.x = cvt2(a.x, a.y);
  r.y = cvt2(a.z, a.w);
  r.z = cvt2(b.x, b.y);
  r.w = cvt2(b.z, b.w);
  return r;
}

// ---------------- K1: q_proj (fp32) + zero scores ----------------
__global__ __launch_bounds__(256) void k_qproj(const float* __restrict__ query,
                                               const float* __restrict__ Wq,
                                               float* __restrict__ qp,
                                               float* __restrict__ scores){
  int tid = threadIdx.x;
  int gw = ((blockIdx.x << 8) + tid) >> 6;   // wave id 0..32767
  int lane = tid & 63;
  int b = gw >> 10, o = gw & 1023;
  const float* qr = query + b*HID;
  const float* wr = Wq + (size_t)o*HID;
  float p = 0.f;
#pragma unroll
  for (int i = 0; i < 16; ++i){
    int h = lane + (i << 6);
    p += qr[h]*wr[h];
  }
#pragma unroll
  for (int m = 32; m >= 1; m >>= 1) p += __shfl_xor(p, m, 64);
  if (lane == 0) qp[gw] = p;
  // zero the 65536-entry score buffer: 8 floats per block
  if (tid < 8) scores[(blockIdx.x << 3) + tid] = 0.f;
}

// ---------------- K3: fused k_proj GEMM + tanh + V-dot -> partial scores ----------------
// grid 4096 = 512 m-tiles (128 rows) x 8 n-tiles (128 cols). bf16 MFMA 32x32x16.
// LDS slots are XOR-swizzled: physical = (kg<<7) | (row ^ kg)  (row low 3 bits).
// Write phase (8 lanes): kg=tid&7 varies, row fixed -> quad = tid&7, conflict-free.
// Read phase (8 lanes): kg fixed, row=l31 varies -> quad = (l31^kg)&7, conflict-free.
__global__ __launch_bounds__(256) void k_scores(const float* __restrict__ keys,
                                                const float* __restrict__ Wk,
                                                const float* __restrict__ qp,
                                                const float* __restrict__ V,
                                                float* __restrict__ scores){
  __shared__ uint4 Ab[2][1024];   // [buf][swizzled(kg*128+row)] : 16B = 8 bf16 (k-contig)
  __shared__ uint4 Bb[2][1024];
  int bid = blockIdx.x;
  // XCD-chunked swizzle (4096 % 8 == 0 -> bijective): keeps the 8 n-variants of
  // an m-strip temporally adjacent on one XCD (keys L2 reuse).
  int v = ((bid & 7) << 9) | (bid >> 3);
  int mt = v >> 3, nt = v & 7;
  int m0 = mt << 7, n0 = nt << 7;
  int b = m0 >> 11;                 // 128 | 2048 -> whole tile in one batch
  int tid = threadIdx.x;
  int lane = tid & 63;
  int wid = tid >> 6;
  int wm = wid >> 1, wn = wid & 1;  // 2x2 wave grid, wave tile 64x64
  int l31 = lane & 31, hi = lane >> 5;

  int skg[4], srw[4];
#pragma unroll
  for (int i = 0; i < 4; ++i){
    int sidx = (i << 8) + tid;      // 1024 slots per tile
    skg[i] = sidx & 7;              // k-group (8 per BK=64)
    srw[i] = sidx >> 3;             // row/col 0..127
  }
  float4 ar[4][2], br[4][2];

  auto loadt = [&](int kt){
#pragma unroll
    for (int i = 0; i < 4; ++i){
      const float* as = keys + (size_t)(m0 + srw[i])*HID + (kt << 6) + (skg[i] << 3);
      ar[i][0] = *(const float4*)as;
      ar[i][1] = *(const float4*)(as + 4);
      const float* bs2 = Wk + (size_t)(n0 + srw[i])*HID + (kt << 6) + (skg[i] << 3);
      br[i][0] = *(const float4*)bs2;
      br[i][1] = *(const float4*)(bs2 + 4);
    }
  };
  auto writet = [&](int bsel){
#pragma unroll
    for (int i = 0; i < 4; ++i){
      int slot = (skg[i] << 7) | (srw[i] ^ skg[i]);   // XOR-swizzled
      Ab[bsel][slot] = pack8(ar[i][0], ar[i][1]);
      Bb[bsel][slot] = pack8(br[i][0], br[i][1]);
    }
  };

  v16f acc[2][2] = {};

  loadt(0);
  writet(0);
  __syncthreads();
  for (int kt = 0; kt < 16; ++kt){
    int bs = kt & 1;
    if (kt < 15) loadt(kt + 1);          // issue next tile's loads early
#pragma unroll
    for (int ks = 0; ks < 4; ++ks){
      int kg = (ks << 1) + hi;           // lane k-group: hi lanes take k+8..15
      int rsw = l31 ^ kg;                // XOR-swizzled row low bits
      int abase = (kg << 7) + (wm << 6) + rsw;
      int bbase = (kg << 7) + (wn << 6) + rsw;
      v8s a0 = __builtin_bit_cast(v8s, Ab[bs][abase]);
      v8s a1 = __builtin_bit_cast(v8s, Ab[bs][abase + 32]);
      v8s b0 = __builtin_bit_cast(v8s, Bb[bs][bbase]);
      v8s b1 = __builtin_bit_cast(v8s, Bb[bs][bbase + 32]);
      acc[0][0] = __builtin_amdgcn_mfma_f32_32x32x16_bf16(a0, b0, acc[0][0], 0, 0, 0);
      acc[0][1] = __builtin_amdgcn_mfma_f32_32x32x16_bf16(a0, b1, acc[0][1], 0, 0, 0);
      acc[1][0] = __builtin_amdgcn_mfma_f32_32x32x16_bf16(a1, b0, acc[1][0], 0, 0, 0);
      acc[1][1] = __builtin_amdgcn_mfma_f32_32x32x16_bf16(a1, b1, acc[1][1], 0, 0, 0);
    }
    if (kt < 15){
      __syncthreads();
      writet(bs ^ 1);
      __syncthreads();
    }
  }

  // epilogue: score_partial[row] += sum_o V[o]*tanh(qp[b][o] + kproj)
  float qpv[2], Vv[2];
#pragma unroll
  for (int ni = 0; ni < 2; ++ni){
    int o = n0 + (wn << 6) + (ni << 5) + l31;
    qpv[ni] = qp[(b << 10) + o];
    Vv[ni] = V[o];
  }
#pragma unroll
  for (int mi = 0; mi < 2; ++mi){
#pragma unroll
    for (int r = 0; r < 16; ++r){
      float sp = 0.f;
#pragma unroll
      for (int ni = 0; ni < 2; ++ni){
        float x = qpv[ni] + acc[mi][ni][r];
        float e = __expf(2.f*x);             // tanh = 1 - 2/(e^{2x}+1); inf-safe
        sp += Vv[ni]*(1.f - 2.f/(e + 1.f));
      }
#pragma unroll
      for (int m = 16; m >= 1; m >>= 1) sp += __shfl_xor(sp, m, 64);  // reduce 32 cols
      if (l31 == 0){
        // C/D map (32x32): col=lane&31, row=(r&3)+8*(r>>2)+4*hi
        int row = m0 + (wm << 6) + (mi << 5) + (r & 3) + ((r >> 2) << 3) + (hi << 2);
        atomicAdd(&scores[row], sp);
      }
    }
  }
}

// ---------------- K4: softmax over S per batch + zero context region ----------------
__global__ __launch_bounds__(256) void k_softmax(const float* __restrict__ scores,
                                                 float* __restrict__ out){
  int b = blockIdx.x; int tid = threadIdx.x;
  __shared__ float red[8];
  const float* srow = scores + b*NS;
  float vv[8];
  float mx = -1e30f;
#pragma unroll
  for (int i = 0; i < 8; ++i){ vv[i] = srow[tid + (i << 8)]; mx = fmaxf(mx, vv[i]); }
#pragma unroll
  for (int m = 32; m >= 1; m >>= 1) mx = fmaxf(mx, __shfl_xor(mx, m, 64));
  int wid = tid >> 6, lane = tid & 63;
  if (lane == 0) red[wid] = mx;
  __syncthreads();
  mx = fmaxf(fmaxf(red[0], red[1]), fmaxf(red[2], red[3]));
  float s = 0.f;
#pragma unroll
  for (int i = 0; i < 8; ++i){ vv[i] = __expf(vv[i] - mx); s += vv[i]; }
#pragma unroll
  for (int m = 32; m >= 1; m >>= 1) s += __shfl_xor(s, m, 64);
  if (lane == 0) red[4 + wid] = s;
  __syncthreads();
  s = red[4] + red[5] + red[6] + red[7];
  float inv = 1.f/s;
  float* wout = out + NB*HID + b*NS;
#pragma unroll
  for (int i = 0; i < 8; ++i) wout[tid + (i << 8)] = vv[i]*inv;
  // zero context region for this batch (K5 accumulates into it)
  float4* ctx = (float4*)(out + b*HID);
  ctx[tid] = make_float4(0.f, 0.f, 0.f, 0.f);
}

// ---------------- K5: context = weights @ keys (fp32) ----------------
__global__ __launch_bounds__(256) void k_context(const float* __restrict__ keys,
                                                 const float* __restrict__ w,
                                                 float* __restrict__ ctx){
  int blk = blockIdx.x;                 // 32 b x 4 hc x 8 sc
  int b = blk >> 5;
  int hc = (blk >> 3) & 3;
  int sc = blk & 7;
  int h = (hc << 8) + threadIdx.x;
  const float* wrow = w + b*NS + (sc << 8);
  const float* krow = keys + ((size_t)b*NS + (sc << 8))*HID + h;
  float a = 0.f;
#pragma unroll 4
  for (int s = 0; s < 256; ++s) a += wrow[s]*krow[(size_t)s*HID];
  atomicAdd(&ctx[b*HID + h], a);
}

extern "C" void kernel_launch(void* const* d_in, const int* in_sizes, int n_in,
                              void* d_out, int out_size, void* d_ws, size_t ws_size,
                              hipStream_t stream){
  const float* query = (const float*)d_in[0];
  const float* keys  = (const float*)d_in[1];
  const float* Wq    = (const float*)d_in[2];
  const float* Wk    = (const float*)d_in[3];
  const float* V     = (const float*)d_in[4];
  float* out = (float*)d_out;
  float* qp = (float*)d_ws;              // 32*1024 f32
  float* scores = qp + NB*HID;           // 32*2048 f32

  hipLaunchKernelGGL(k_qproj,   dim3(8192), dim3(256), 0, stream, query, Wq, qp, scores);
  hipLaunchKernelGGL(k_scores,  dim3(4096), dim3(256), 0, stream, keys, Wk, qp, V, scores);
  hipLaunchKernelGGL(k_softmax, dim3(32),   dim3(256), 0, stream, scores, out);
  hipLaunchKernelGGL(k_context, dim3(1024), dim3(256), 0, stream, keys, out + NB*HID, out);
}

// Round 5
// 681.104 us; speedup vs baseline: 1.1409x; 1.1370x over previous
//
#include <hip/hip_runtime.h>
#include <hip/hip_bf16.h>
#include <stdint.h>

#define HID 1024
#define NB 32
#define NS 2048

typedef short v8s __attribute__((ext_vector_type(8)));    // 8 x bf16 bits
typedef float v16f __attribute__((ext_vector_type(16)));  // 32x32 MFMA acc
typedef const __attribute__((address_space(1))) void* gas_t;
typedef __attribute__((address_space(3))) void* las_t;

// direct global->LDS DMA, 16B per lane. LDS dest = wave-uniform base + lane*16.
__device__ __forceinline__ void gload16(const void* g, void* l){
  __builtin_amdgcn_global_load_lds((gas_t)g, (las_t)l, 16, 0, 0);
}

// packed f32x2 -> bf16x2 (RNE), 1 VALU op. Pair-order swap (if any) is applied
// identically to keys and Wk -> k-permutation cancels in the dot product.
__device__ __forceinline__ unsigned cvt2(float a, float b){
  unsigned r;
  asm("v_cvt_pk_bf16_f32 %0, %1, %2" : "=v"(r) : "v"(a), "v"(b));
  return r;
}

__device__ __forceinline__ uint4 pack8(const float4& a, const float4& b){
  uint4 r;
  r.x = cvt2(a.x, a.y);
  r.y = cvt2(a.z, a.w);
  r.z = cvt2(b.x, b.y);
  r.w = cvt2(b.z, b.w);
  return r;
}

// ---------------- K0: fp32 -> bf16 streaming convert ----------------
__global__ __launch_bounds__(256) void k_conv(const float* __restrict__ src,
                                              ushort* __restrict__ dst, int n8){
  int i0 = (blockIdx.x << 8) + threadIdx.x;
  int stride = gridDim.x << 8;
  for (int i = i0; i < n8; i += stride){
    const float4* s = (const float4*)(src + (size_t)i*8);
    float4 a = s[0], b = s[1];
    *(uint4*)(dst + (size_t)i*8) = pack8(a, b);
  }
}

// ---------------- K1: q_proj (fp32) + zero scores ----------------
__global__ __launch_bounds__(256) void k_qproj(const float* __restrict__ query,
                                               const float* __restrict__ Wq,
                                               float* __restrict__ qp,
                                               float* __restrict__ scores){
  int tid = threadIdx.x;
  int gw = ((blockIdx.x << 8) + tid) >> 6;   // wave id 0..32767
  int lane = tid & 63;
  int b = gw >> 10, o = gw & 1023;
  const float* qr = query + b*HID;
  const float* wr = Wq + (size_t)o*HID;
  float p = 0.f;
#pragma unroll
  for (int i = 0; i < 16; ++i){
    int h = lane + (i << 6);
    p += qr[h]*wr[h];
  }
#pragma unroll
  for (int m = 32; m >= 1; m >>= 1) p += __shfl_xor(p, m, 64);
  if (lane == 0) qp[gw] = p;
  if (tid < 8) scores[(blockIdx.x << 3) + tid] = 0.f;
}

// ---------------- K3 (main): m97-structure fused GEMM+tanh+V-dot ----------------
// 128x128 tile, BK=64 bf16, single-buffer 32KB LDS, global_load_lds width 16,
// 2 barriers per K-step, 4 blocks/CU. LDS linear [row][chunk] (128B rows);
// 16B chunks XOR-swizzled via PRE-SWIZZLED GLOBAL SOURCE: phys chunk pc holds
// logical chunk pc^(row&7). ds_read uses the same XOR -> conflict-free.
__global__ __launch_bounds__(256, 4) void k_scores2(const ushort* __restrict__ keysb,
                                                    const ushort* __restrict__ Wkb,
                                                    const float* __restrict__ qp,
                                                    const float* __restrict__ V,
                                                    float* __restrict__ scores){
  __shared__ uint4 Ab[1024];   // 16KB: slot s=row*8+pc at byte s*16
  __shared__ uint4 Bb[1024];
  int bid = blockIdx.x;
  // XCD-chunked bijective swizzle (4096 % 8 == 0)
  int v = ((bid & 7) << 9) | (bid >> 3);
  int mt = v >> 3, nt = v & 7;
  int m0 = mt << 7, n0 = nt << 7;
  int b = m0 >> 11;
  int tid = threadIdx.x;
  int lane = tid & 63;
  int wid = tid >> 6;
  int wm = wid >> 1, wn = wid & 1;  // 2x2 waves, 64x64 each
  int l31 = lane & 31, hi = lane >> 5;

  v16f acc[2][2] = {};

  for (int kt = 0; kt < 16; ++kt){
    // stage: 4+4 gload16 per wave; per-lane global addr carries the XOR swizzle
#pragma unroll
    for (int j = 0; j < 4; ++j){
      int s = (wid << 8) + (j << 6) + lane;    // slot 0..1023
      int row = s >> 3;
      int lc = (s & 7) ^ (row & 7);            // logical k-chunk for this phys slot
      size_t goff = (size_t)row*HID + (kt << 6) + (lc << 3);
      char* lb = (char*)Ab + (((wid << 2) + j) << 10);   // wave-uniform base
      gload16(keysb + (size_t)m0*HID + goff, lb);
      char* lb2 = (char*)Bb + (((wid << 2) + j) << 10);
      gload16(Wkb + (size_t)n0*HID + goff, lb2);
    }
    __syncthreads();   // drains vmcnt(0): tile landed
#pragma unroll
    for (int ks = 0; ks < 4; ++ks){
      int kg = (ks << 1) + hi;                 // logical k-chunk 0..7
      int ra = (wm << 6) + l31;
      int rb = (wn << 6) + l31;
      int offA = ra*128 + ((kg ^ (ra & 7)) << 4);   // (ra+32)&7 == ra&7
      int offB = rb*128 + ((kg ^ (rb & 7)) << 4);
      v8s a0 = __builtin_bit_cast(v8s, *(const uint4*)((const char*)Ab + offA));
      v8s a1 = __builtin_bit_cast(v8s, *(const uint4*)((const char*)Ab + offA + 4096));
      v8s b0 = __builtin_bit_cast(v8s, *(const uint4*)((const char*)Bb + offB));
      v8s b1 = __builtin_bit_cast(v8s, *(const uint4*)((const char*)Bb + offB + 4096));
      acc[0][0] = __builtin_amdgcn_mfma_f32_32x32x16_bf16(a0, b0, acc[0][0], 0, 0, 0);
      acc[0][1] = __builtin_amdgcn_mfma_f32_32x32x16_bf16(a0, b1, acc[0][1], 0, 0, 0);
      acc[1][0] = __builtin_amdgcn_mfma_f32_32x32x16_bf16(a1, b0, acc[1][0], 0, 0, 0);
      acc[1][1] = __builtin_amdgcn_mfma_f32_32x32x16_bf16(a1, b1, acc[1][1], 0, 0, 0);
    }
    __syncthreads();   // all waves done reading before next stage overwrites
  }

  // epilogue: scores[row] += sum_o V[o]*tanh(qp[b][o] + kproj)  (validated R1/R3)
  float qpv[2], Vv[2];
#pragma unroll
  for (int ni = 0; ni < 2; ++ni){
    int o = n0 + (wn << 6) + (ni << 5) + l31;
    qpv[ni] = qp[(b << 10) + o];
    Vv[ni] = V[o];
  }
#pragma unroll
  for (int mi = 0; mi < 2; ++mi){
#pragma unroll
    for (int r = 0; r < 16; ++r){
      float sp = 0.f;
#pragma unroll
      for (int ni = 0; ni < 2; ++ni){
        float x = qpv[ni] + acc[mi][ni][r];
        float e = __expf(2.f*x);
        sp += Vv[ni]*(1.f - 2.f/(e + 1.f));
      }
#pragma unroll
      for (int m = 16; m >= 1; m >>= 1) sp += __shfl_xor(sp, m, 64);
      if (l31 == 0){
        int row = m0 + (wm << 6) + (mi << 5) + (r & 3) + ((r >> 2) << 3) + (hi << 2);
        atomicAdd(&scores[row], sp);
      }
    }
  }
}

// ---------------- K3 (fallback if ws too small): R3 reg-staged fp32 ----------------
__global__ __launch_bounds__(256) void k_scores_fb(const float* __restrict__ keys,
                                                   const float* __restrict__ Wk,
                                                   const float* __restrict__ qp,
                                                   const float* __restrict__ V,
                                                   float* __restrict__ scores){
  __shared__ uint4 Ab[2][1024];
  __shared__ uint4 Bb[2][1024];
  int bid = blockIdx.x;
  int v = ((bid & 7) << 9) | (bid >> 3);
  int mt = v >> 3, nt = v & 7;
  int m0 = mt << 7, n0 = nt << 7;
  int b = m0 >> 11;
  int tid = threadIdx.x;
  int lane = tid & 63;
  int wid = tid >> 6;
  int wm = wid >> 1, wn = wid & 1;
  int l31 = lane & 31, hi = lane >> 5;

  int skg[4], srw[4];
#pragma unroll
  for (int i = 0; i < 4; ++i){
    int sidx = (i << 8) + tid;
    skg[i] = sidx & 7;
    srw[i] = sidx >> 3;
  }
  float4 ar[4][2], br[4][2];
  auto loadt = [&](int kt){
#pragma unroll
    for (int i = 0; i < 4; ++i){
      const float* as = keys + (size_t)(m0 + srw[i])*HID + (kt << 6) + (skg[i] << 3);
      ar[i][0] = *(const float4*)as;
      ar[i][1] = *(const float4*)(as + 4);
      const float* bs2 = Wk + (size_t)(n0 + srw[i])*HID + (kt << 6) + (skg[i] << 3);
      br[i][0] = *(const float4*)bs2;
      br[i][1] = *(const float4*)(bs2 + 4);
    }
  };
  auto writet = [&](int bsel){
#pragma unroll
    for (int i = 0; i < 4; ++i){
      int slot = (skg[i] << 7) | (srw[i] ^ skg[i]);
      Ab[bsel][slot] = pack8(ar[i][0], ar[i][1]);
      Bb[bsel][slot] = pack8(br[i][0], br[i][1]);
    }
  };
  v16f acc[2][2] = {};
  loadt(0); writet(0); __syncthreads();
  for (int kt = 0; kt < 16; ++kt){
    int bs = kt & 1;
    if (kt < 15) loadt(kt + 1);
#pragma unroll
    for (int ks = 0; ks < 4; ++ks){
      int kg = (ks << 1) + hi;
      int rsw = l31 ^ kg;
      int abase = (kg << 7) + (wm << 6) + rsw;
      int bbase = (kg << 7) + (wn << 6) + rsw;
      v8s a0 = __builtin_bit_cast(v8s, Ab[bs][abase]);
      v8s a1 = __builtin_bit_cast(v8s, Ab[bs][abase + 32]);
      v8s b0 = __builtin_bit_cast(v8s, Bb[bs][bbase]);
      v8s b1 = __builtin_bit_cast(v8s, Bb[bs][bbase + 32]);
      acc[0][0] = __builtin_amdgcn_mfma_f32_32x32x16_bf16(a0, b0, acc[0][0], 0, 0, 0);
      acc[0][1] = __builtin_amdgcn_mfma_f32_32x32x16_bf16(a0, b1, acc[0][1], 0, 0, 0);
      acc[1][0] = __builtin_amdgcn_mfma_f32_32x32x16_bf16(a1, b0, acc[1][0], 0, 0, 0);
      acc[1][1] = __builtin_amdgcn_mfma_f32_32x32x16_bf16(a1, b1, acc[1][1], 0, 0, 0);
    }
    if (kt < 15){
      __syncthreads();
      writet(bs ^ 1);
      __syncthreads();
    }
  }
  float qpv[2], Vv[2];
#pragma unroll
  for (int ni = 0; ni < 2; ++ni){
    int o = n0 + (wn << 6) + (ni << 5) + l31;
    qpv[ni] = qp[(b << 10) + o];
    Vv[ni] = V[o];
  }
#pragma unroll
  for (int mi = 0; mi < 2; ++mi){
#pragma unroll
    for (int r = 0; r < 16; ++r){
      float sp = 0.f;
#pragma unroll
      for (int ni = 0; ni < 2; ++ni){
        float x = qpv[ni] + acc[mi][ni][r];
        float e = __expf(2.f*x);
        sp += Vv[ni]*(1.f - 2.f/(e + 1.f));
      }
#pragma unroll
      for (int m = 16; m >= 1; m >>= 1) sp += __shfl_xor(sp, m, 64);
      if (l31 == 0){
        int row = m0 + (wm << 6) + (mi << 5) + (r & 3) + ((r >> 2) << 3) + (hi << 2);
        atomicAdd(&scores[row], sp);
      }
    }
  }
}

// ---------------- K4: softmax per batch + zero context region ----------------
__global__ __launch_bounds__(256) void k_softmax(const float* __restrict__ scores,
                                                 float* __restrict__ out){
  int b = blockIdx.x; int tid = threadIdx.x;
  __shared__ float red[8];
  const float* srow = scores + b*NS;
  float vv[8];
  float mx = -1e30f;
#pragma unroll
  for (int i = 0; i < 8; ++i){ vv[i] = srow[tid + (i << 8)]; mx = fmaxf(mx, vv[i]); }
#pragma unroll
  for (int m = 32; m >= 1; m >>= 1) mx = fmaxf(mx, __shfl_xor(mx, m, 64));
  int wid = tid >> 6, lane = tid & 63;
  if (lane == 0) red[wid] = mx;
  __syncthreads();
  mx = fmaxf(fmaxf(red[0], red[1]), fmaxf(red[2], red[3]));
  float s = 0.f;
#pragma unroll
  for (int i = 0; i < 8; ++i){ vv[i] = __expf(vv[i] - mx); s += vv[i]; }
#pragma unroll
  for (int m = 32; m >= 1; m >>= 1) s += __shfl_xor(s, m, 64);
  if (lane == 0) red[4 + wid] = s;
  __syncthreads();
  s = red[4] + red[5] + red[6] + red[7];
  float inv = 1.f/s;
  float* wout = out + NB*HID + b*NS;
#pragma unroll
  for (int i = 0; i < 8; ++i) wout[tid + (i << 8)] = vv[i]*inv;
  float4* ctx = (float4*)(out + b*HID);
  ctx[tid] = make_float4(0.f, 0.f, 0.f, 0.f);
}

// ---------------- K5: context = weights @ keys (fp32, coalesced rows) ----------------
// block = (b, sc): 128 s-rows; 256 threads each own a float4 h-chunk (full 1024 h).
__global__ __launch_bounds__(256) void k_context2(const float* __restrict__ keys,
                                                  const float* __restrict__ w,
                                                  float* __restrict__ ctx){
  __shared__ float ws[128];
  int blk = blockIdx.x;                 // 512 = 32 b x 16 sc
  int b = blk >> 4, sc = blk & 15;
  int s0 = sc << 7;
  int tid = threadIdx.x;
  if (tid < 128) ws[tid] = w[b*NS + s0 + tid];
  __syncthreads();
  const float4* kp = (const float4*)(keys + ((size_t)b*NS + s0)*HID) + tid;
  float4 a = make_float4(0.f, 0.f, 0.f, 0.f);
#pragma unroll 8
  for (int s = 0; s < 128; ++s){
    float4 kv = kp[(size_t)s*256];
    float wv = ws[s];
    a.x += wv*kv.x; a.y += wv*kv.y; a.z += wv*kv.z; a.w += wv*kv.w;
  }
  float* o = ctx + b*HID + (tid << 2);
  atomicAdd(o, a.x); atomicAdd(o + 1, a.y); atomicAdd(o + 2, a.z); atomicAdd(o + 3, a.w);
}

extern "C" void kernel_launch(void* const* d_in, const int* in_sizes, int n_in,
                              void* d_out, int out_size, void* d_ws, size_t ws_size,
                              hipStream_t stream){
  const float* query = (const float*)d_in[0];
  const float* keys  = (const float*)d_in[1];
  const float* Wq    = (const float*)d_in[2];
  const float* Wk    = (const float*)d_in[3];
  const float* V     = (const float*)d_in[4];
  float* out = (float*)d_out;
  float* qp = (float*)d_ws;                       // 32K f32
  float* scores = qp + NB*HID;                    // 64K f32
  ushort* keysb = (ushort*)((char*)d_ws + ((size_t)NB*HID + (size_t)NB*NS)*4);
  ushort* Wkb = keysb + (size_t)NB*NS*HID;
  const size_t WS_NEED = ((size_t)NB*HID + (size_t)NB*NS)*4
                       + ((size_t)NB*NS*HID + (size_t)HID*HID)*2;  // 136,708,096

  hipLaunchKernelGGL(k_qproj, dim3(8192), dim3(256), 0, stream, query, Wq, qp, scores);
  if (ws_size >= WS_NEED){
    hipLaunchKernelGGL(k_conv, dim3(2048), dim3(256), 0, stream, keys, keysb, NB*NS*HID/8);
    hipLaunchKernelGGL(k_conv, dim3(256),  dim3(256), 0, stream, Wk, Wkb, HID*HID/8);
    hipLaunchKernelGGL(k_scores2, dim3(4096), dim3(256), 0, stream, keysb, Wkb, qp, V, scores);
  } else {
    hipLaunchKernelGGL(k_scores_fb, dim3(4096), dim3(256), 0, stream, keys, Wk, qp, V, scores);
  }
  hipLaunchKernelGGL(k_softmax, dim3(32), dim3(256), 0, stream, scores, out);
  hipLaunchKernelGGL(k_context2, dim3(512), dim3(256), 0, stream, keys, out + NB*HID, out);
}